// Round 8
// baseline (62.964 us; speedup 1.0000x reference)
//
#include <hip/hip_runtime.h>

#define WINDOW 48
#define RES 50
#define PRED 96
#define SEG 100
#define BATCH 2048
#define KTOT 4800
#define KTRUNC 12

#define KSPLIT 16
#define KR 300        // k-range per block
#define KC 60         // staged chunk
#define NQ 15         // float4-quads per row per chunk
#define XROW 292      // Xs row stride per k-quad (floats): 256 + 36 pad -> 2-way banks

// ws float offsets
#define OFF_M   0        // [50][48]      2400
#define OFF_DJ  2400     // [100][64]     6400   Dj[j][r] = d_r^(99-j)
#define OFF_DK  8800     // [16][50]      800    Dk[k][r] = d_r^(100k)
#define OFF_WT  9600     // [50][96]      4800   Wt[r][o] = W_out[o][r]
#define OFF_KT  14400    // [4800][64]    307200 Kt[k][r] = Dj[k/48][r]*M[r][k%48]
#define OFF_LP  321600   // [16][2048][52] 1703936
#define OFF_L   2025536  // [2048][52]    106496
// total 2132032 floats = 8.53 MB

__device__ __forceinline__ float ipow(float b, int n) {
    float r = 1.f, p = b;
    while (n) { if (n & 1) r *= p; p *= p; n >>= 1; }
    return r;
}

__global__ __launch_bounds__(256) void k0a(const float* __restrict__ W_lin,
                                           const float* __restrict__ W_in,
                                           const float* __restrict__ d,
                                           const float* __restrict__ W_out,
                                           float* __restrict__ ws) {
    int f = blockIdx.x * 256 + threadIdx.x;
    if (f < 2400) {                       // M[r][w]
        int r = f / WINDOW, w = f % WINDOW;
        float acc = 0.f;
        for (int v = 0; v < WINDOW; ++v)
            acc = fmaf(W_in[r * WINDOW + v], W_lin[v * WINDOW + w], acc);
        ws[OFF_M + f] = acc;
    } else if (f < 8800) {                // Dj[j][r] = d_r^(99-j)
        int e = f - 2400;
        int j = e >> 6, r = e & 63;
        ws[OFF_DJ + e] = (r < RES) ? ipow(d[r], 99 - j) : 0.f;
    } else if (f < 9600) {                // Dk[k][r] = (d_r^100)^k
        int e = f - 8800;
        int k = e / RES, r = e % RES;
        ws[OFF_DK + e] = ipow(ipow(d[r], 100), k);
    } else if (f < 14400) {               // Wt[r][o]
        int e = f - 9600;
        int r = e / PRED, o = e % PRED;
        ws[OFF_WT + e] = W_out[o * RES + r];
    }
}

__global__ __launch_bounds__(256) void k0b(float* __restrict__ ws) {
    const float* M  = ws + OFF_M;
    const float* Dj = ws + OFF_DJ;
    float* Kt = ws + OFF_KT;
    for (int e = blockIdx.x * 256 + threadIdx.x; e < KTOT * 64; e += gridDim.x * 256) {
        int k = e >> 6, r = e & 63;
        int j = k / WINDOW, w = k - j * WINDOW;
        Kt[e] = (r < RES) ? Dj[j * 64 + r] * M[r * WINDOW + w] : 0.f;
    }
}

// GEMM Lp[s][b][c] = sum_{k in split s} x[b][k] * Kt[k][c]
// grid 512 = 32 m-tiles x 16 k-splits; block 256 = 4 waves; lane = batch (64/block).
// Wave w covers channels [clo..chi] via 16 accs at base c0a=12w (3 wasted).
// X: quad-packed transposed LDS tile, one ds_read_b128 per 4k per lane.
// K: wave-uniform float4 loads (L1/scalar pipe) - no LDS for K.
__global__ __launch_bounds__(256, 2) void k1_gemm(const float* __restrict__ x,
                                                  const float* __restrict__ ws,
                                                  float* __restrict__ lp) {
    __shared__ float Xs[NQ * XROW];       // 17.5 KB
    const float* Kt = ws + OFF_KT;
    int bid = blockIdx.x;
    int s  = bid & (KSPLIT - 1);
    int mt = bid >> 4;
    int b0 = mt * 64;
    int t = threadIdx.x;
    int w = t >> 6;
    int lane = t & 63;

    int c0a = __builtin_amdgcn_readfirstlane(12 * w);      // 0,12,24,36
    int clo = __builtin_amdgcn_readfirstlane((w == 0) ? 0 : (w == 1) ? 13 : (w == 2) ? 26 : 39);
    int chi = __builtin_amdgcn_readfirstlane((w == 0) ? 12 : (w == 1) ? 25 : (w == 2) ? 38 : 49);

    float acc[16];
#pragma unroll
    for (int i = 0; i < 16; ++i) acc[i] = 0.f;

    int kbase = s * KR;
    for (int ch = 0; ch < 5; ++ch) {
        int kb = kbase + ch * KC;
        __syncthreads();                   // prev-iter reads done before overwrite
        for (int e4 = t; e4 < 64 * NQ; e4 += 256) {
            int b = e4 / NQ;
            int kq = e4 - b * NQ;
            float4 v = *(const float4*)(x + (size_t)(b0 + b) * KTOT + kb + 4 * kq);
            *(float4*)(Xs + kq * XROW + 4 * b) = v;   // banks (4kq+4b)%32 -> 2-way
        }
        __syncthreads();

        const float* xaddr = Xs + 4 * lane;
        for (int k4 = 0; k4 < NQ; ++k4) {
            float4 xq = *(const float4*)(xaddr + k4 * XROW);
            const float4* kr0 = (const float4*)(Kt + (size_t)(kb + 4 * k4) * 64 + c0a);
#pragma unroll
            for (int i = 0; i < 4; ++i) {
                float xv = (i == 0) ? xq.x : (i == 1) ? xq.y : (i == 2) ? xq.z : xq.w;
                float4 k0v = kr0[i * 16 + 0];
                float4 k1v = kr0[i * 16 + 1];
                float4 k2v = kr0[i * 16 + 2];
                float4 k3v = kr0[i * 16 + 3];
                acc[0]  = fmaf(xv, k0v.x, acc[0]);
                acc[1]  = fmaf(xv, k0v.y, acc[1]);
                acc[2]  = fmaf(xv, k0v.z, acc[2]);
                acc[3]  = fmaf(xv, k0v.w, acc[3]);
                acc[4]  = fmaf(xv, k1v.x, acc[4]);
                acc[5]  = fmaf(xv, k1v.y, acc[5]);
                acc[6]  = fmaf(xv, k1v.z, acc[6]);
                acc[7]  = fmaf(xv, k1v.w, acc[7]);
                acc[8]  = fmaf(xv, k2v.x, acc[8]);
                acc[9]  = fmaf(xv, k2v.y, acc[9]);
                acc[10] = fmaf(xv, k2v.z, acc[10]);
                acc[11] = fmaf(xv, k2v.w, acc[11]);
                acc[12] = fmaf(xv, k3v.x, acc[12]);
                acc[13] = fmaf(xv, k3v.y, acc[13]);
                acc[14] = fmaf(xv, k3v.z, acc[14]);
                acc[15] = fmaf(xv, k3v.w, acc[15]);
            }
        }
    }

    float* dst = lp + ((size_t)s * BATCH + (b0 + lane)) * 52;
#pragma unroll
    for (int i = 0; i < 16; ++i) {
        int c = c0a + i;
        if (c >= clo && c <= chi) dst[c] = acc[i];
    }
}

// L[b][c] = sum_s Lp[s][b][c]  (x4-vectorized)
__global__ __launch_bounds__(256) void k2a(float* __restrict__ ws) {
    const float4* lp4 = (const float4*)(ws + OFF_LP);
    float4* l4 = (float4*)(ws + OFF_L);
    int e4 = blockIdx.x * 256 + threadIdx.x;   // < 26624
    float4 s = lp4[e4];
#pragma unroll
    for (int sp = 1; sp < KSPLIT; ++sp) {
        float4 v = lp4[(size_t)sp * 26624 + e4];
        s.x += v.x; s.y += v.y; s.z += v.z; s.w += v.w;
    }
    l4[e4] = s;
}

// s[r] = sum_k Dk[k][r]*L[b-k][r]; out[b][o] = sum_r s[r]*Wt[r][o]
__global__ __launch_bounds__(128) void k2b(const float* __restrict__ ws,
                                           float* __restrict__ out) {
    const float* L  = ws + OFF_L;
    const float* Dk = ws + OFF_DK;
    const float* Wt = ws + OFF_WT;
    __shared__ float s_s[52];
    int b = blockIdx.x;
    int t = threadIdx.x;
    if (t < RES) {
        float acc = 0.f;
#pragma unroll
        for (int k = 0; k < KTRUNC; ++k) {
            int bb = b - k;
            if (bb >= 0) acc = fmaf(Dk[k * RES + t], L[bb * 52 + t], acc);
        }
        s_s[t] = acc;
    }
    __syncthreads();
    if (t < PRED) {
        float acc = 0.f;
#pragma unroll 10
        for (int r = 0; r < RES; ++r)
            acc = fmaf(s_s[r], Wt[r * PRED + t], acc);
        out[b * PRED + t] = acc;
    }
}

extern "C" void kernel_launch(void* const* d_in, const int* in_sizes, int n_in,
                              void* d_out, int out_size, void* d_ws, size_t ws_size,
                              hipStream_t stream) {
    const float* x     = (const float*)d_in[0];
    const float* W_lin = (const float*)d_in[1];
    const float* W_in  = (const float*)d_in[2];
    const float* d     = (const float*)d_in[3];
    const float* W_out = (const float*)d_in[4];
    float* out = (float*)d_out;
    float* ws  = (float*)d_ws;
    float* lp  = ws + OFF_LP;

    k0a<<<57, 256, 0, stream>>>(W_lin, W_in, d, W_out, ws);
    k0b<<<512, 256, 0, stream>>>(ws);
    k1_gemm<<<512, 256, 0, stream>>>(x, ws, lp);
    k2a<<<104, 256, 0, stream>>>(ws);
    k2b<<<BATCH, 128, 0, stream>>>(ws, out);
}

// Round 9
// 42.630 us; speedup vs baseline: 1.4770x; 1.4770x over previous
//
#include <hip/hip_runtime.h>
#include <hip/hip_bf16.h>

#define WINDOW 48
#define RES 50
#define PRED 96
#define SEG 100
#define BATCH 2048
#define KTOT 4800
#define KTRUNC 12
#define KSPLIT 25
#define KR 192        // k-range per block = 6 steps of 32
#define NSTEP 6

typedef __attribute__((ext_vector_type(8))) short short8v;   // 8 bf16 (4 VGPRs)
typedef __attribute__((ext_vector_type(4))) float f32x4;

// ws float offsets
#define OFF_DK 0          // Dk[16][50]            800
#define OFF_WT 800        // Wt[50][96]            4800  -> 5600
#define OFF_KB 5632       // ushort Kb[64][4800]   153600 floats -> 159232 (16B-aligned)
#define OFF_LP 159232     // Lp[25][2048][64]      3276800 -> 3436032
#define OFF_L  3436032    // L[2048][64]           131072 -> 3567104 floats = 14.3 MB

__device__ __forceinline__ float ipow(float b, int n) {
    float r = 1.f, p = b;
    while (n) { if (n & 1) r *= p; p *= p; n >>= 1; }
    return r;
}

// Dk[k][r] = d_r^(100k); Wt[r][o] = W_out[o][r]
__global__ __launch_bounds__(256) void k0a(const float* __restrict__ d,
                                           const float* __restrict__ W_out,
                                           float* __restrict__ ws) {
    int f = blockIdx.x * 256 + threadIdx.x;
    if (f < 800) {
        int k = f / RES, r = f % RES;
        ws[OFF_DK + f] = ipow(ipow(d[r], 100), k);
    } else if (f < 5600) {
        int e = f - 800;
        int r = e / PRED, o = e % PRED;
        ws[OFF_WT + e] = W_out[o * RES + r];
    }
}

// Kb[c][k] = bf16( d_c^(99-j) * M[c][w] ), k = 48j + w ; rows c>=50 zero.
__global__ __launch_bounds__(256) void k0b(const float* __restrict__ W_lin,
                                           const float* __restrict__ W_in,
                                           const float* __restrict__ d,
                                           float* __restrict__ ws) {
    unsigned e = blockIdx.x * 256 + threadIdx.x;   // c*4800 + k, < 307200
    int c = e / KTOT, k = e - (e / KTOT) * KTOT;
    float val = 0.f;
    if (c < RES) {
        int j = k / WINDOW, w = k - WINDOW * j;
        float m = 0.f;
        for (int v = 0; v < WINDOW; ++v)
            m = fmaf(W_in[c * WINDOW + v], W_lin[v * WINDOW + w], m);
        val = ipow(d[c], 99 - j) * m;
    }
    __hip_bfloat16 h = __float2bfloat16(val);
    ((unsigned short*)(ws + OFF_KB))[e] = __builtin_bit_cast(unsigned short, h);
}

__device__ __forceinline__ void split8(f32x4 a, f32x4 b, short8v& hi, short8v& lo) {
#pragma unroll
    for (int m = 0; m < 8; ++m) {
        float v = (m < 4) ? a[m] : b[m - 4];
        __hip_bfloat16 h = __float2bfloat16(v);           // RNE
        float hf = __bfloat162float(h);
        __hip_bfloat16 l2 = __float2bfloat16(v - hf);
        hi[m] = (short)__builtin_bit_cast(unsigned short, h);
        lo[m] = (short)__builtin_bit_cast(unsigned short, l2);
    }
}

// One wave per (M-tile mt of 16 rows) x (k-split s of 192 k's). No LDS.
// A-frag: lane l holds x[row=l&15][k = (l>>4)*8 .. +7] — 2 float4/step, split hi/lo bf16.
// B-frag n: lane l holds Kb[col=16n+(l&15)][same 8 k] — one 16B load/step.
// acc[n] += mfma(xhi,B) ; acc[n] += mfma(xlo,B).  C: col=lane&15, row=(lane>>4)*4+i.
__global__ __launch_bounds__(64, 4) void k1_mfma(const float* __restrict__ x,
                                                 const float* __restrict__ ws,
                                                 float* __restrict__ lp) {
    const unsigned short* Kb = (const unsigned short*)(ws + OFF_KB);
    int bid = blockIdx.x;
    int mt = bid / KSPLIT, s = bid - mt * KSPLIT;
    int l = threadIdx.x & 63;
    int row = l & 15, kq = l >> 4;

    // issue all 12 x-loads upfront (20.5 KB/wave in flight)
    const float* xp = x + (size_t)(mt * 16 + row) * KTOT + s * KR + kq * 8;
    f32x4 xr[2 * NSTEP];
#pragma unroll
    for (int t = 0; t < NSTEP; ++t) {
        xr[2 * t]     = *(const f32x4*)(xp + 32 * t);
        xr[2 * t + 1] = *(const f32x4*)(xp + 32 * t + 4);
    }

    const unsigned short* kp = Kb + (size_t)row * KTOT + s * KR + kq * 8;

    f32x4 acc[4];
#pragma unroll
    for (int n = 0; n < 4; ++n) acc[n] = (f32x4)(0.f);

#pragma unroll
    for (int t = 0; t < NSTEP; ++t) {
        short8v ahi, alo;
        split8(xr[2 * t], xr[2 * t + 1], ahi, alo);
#pragma unroll
        for (int n = 0; n < 4; ++n) {
            short8v bv = *(const short8v*)(kp + (size_t)n * 16 * KTOT + 32 * t);
            acc[n] = __builtin_amdgcn_mfma_f32_16x16x32_bf16(ahi, bv, acc[n], 0, 0, 0);
            acc[n] = __builtin_amdgcn_mfma_f32_16x16x32_bf16(alo, bv, acc[n], 0, 0, 0);
        }
    }

    float* dst = lp + ((size_t)s * BATCH + mt * 16) * 64;
#pragma unroll
    for (int n = 0; n < 4; ++n)
#pragma unroll
        for (int i = 0; i < 4; ++i) {
            int rr = kq * 4 + i;          // row in tile
            int cc = n * 16 + row;        // col = channel
            dst[(size_t)rr * 64 + cc] = acc[n][i];
        }
}

// L[b][c] = sum_s Lp[s][b][c]   (float4-vectorized; 32768 float4s)
__global__ __launch_bounds__(256) void k2a(float* __restrict__ ws) {
    int e = blockIdx.x * 256 + threadIdx.x;
    const f32x4* lp4 = (const f32x4*)(ws + OFF_LP);
    f32x4 sum = lp4[e];
#pragma unroll
    for (int sp = 1; sp < KSPLIT; ++sp)
        sum += lp4[(size_t)sp * 32768 + e];
    ((f32x4*)(ws + OFF_L))[e] = sum;
}

// s[r] = sum_k Dk[k][r]*L[b-k][r]; out[b][o] = sum_r s[r]*Wt[r][o]
__global__ __launch_bounds__(128) void k2b(const float* __restrict__ ws,
                                           float* __restrict__ out) {
    const float* L  = ws + OFF_L;
    const float* Dk = ws + OFF_DK;
    const float* Wt = ws + OFF_WT;
    __shared__ float s_s[52];
    int b = blockIdx.x;
    int t = threadIdx.x;
    if (t < RES) {
        float acc = 0.f;
#pragma unroll
        for (int k = 0; k < KTRUNC; ++k) {
            int bb = b - k;
            if (bb >= 0) acc = fmaf(Dk[k * RES + t], L[(size_t)bb * 64 + t], acc);
        }
        s_s[t] = acc;
    }
    __syncthreads();
    if (t < PRED) {
        float acc = 0.f;
#pragma unroll 10
        for (int r = 0; r < RES; ++r)
            acc = fmaf(s_s[r], Wt[r * PRED + t], acc);
        out[b * PRED + t] = acc;
    }
}

extern "C" void kernel_launch(void* const* d_in, const int* in_sizes, int n_in,
                              void* d_out, int out_size, void* d_ws, size_t ws_size,
                              hipStream_t stream) {
    const float* x     = (const float*)d_in[0];
    const float* W_lin = (const float*)d_in[1];
    const float* W_in  = (const float*)d_in[2];
    const float* d     = (const float*)d_in[3];
    const float* W_out = (const float*)d_in[4];
    float* out = (float*)d_out;
    float* ws  = (float*)d_ws;
    float* lp  = ws + OFF_LP;

    k0a<<<22, 256, 0, stream>>>(d, W_out, ws);
    k0b<<<1200, 256, 0, stream>>>(W_lin, W_in, d, ws);
    k1_mfma<<<128 * KSPLIT, 64, 0, stream>>>(x, ws, lp);
    k2a<<<128, 256, 0, stream>>>(ws);
    k2b<<<BATCH, 128, 0, stream>>>(ws, out);
}

// Round 10
// 42.524 us; speedup vs baseline: 1.4807x; 1.0025x over previous
//
#include <hip/hip_runtime.h>
#include <hip/hip_bf16.h>

#define WINDOW 48
#define RES 50
#define PRED 96
#define BATCH 2048
#define KTOT 4800
#define KPAD 5120
#define KTRUNC 12
#define KS 8          // k-splits (grid)
#define KRB 640       // k-range per block (4 waves x 5 steps x 32)
#define XSTR 644      // LDS row stride (floats), 16B-aligned

typedef __attribute__((ext_vector_type(8))) short short8v;   // 8 bf16
typedef __attribute__((ext_vector_type(4))) float f32x4;

// ws float offsets
#define OFF_DK 0          // Dk[16][50]           800
#define OFF_WT 800        // Wt[50][96]           4800  -> 5600
#define OFF_M  5600       // M[50][48]            2400  -> 8000
#define OFF_KB 8000       // ushort Kb[64][5120]  163840 floats -> 171840
#define OFF_LP 171840     // Lp[8][2048][64]      1048576 -> 1220416
#define OFF_L  1220416    // L[2048][64]          131072 -> 1351488 floats (5.4 MB)

__device__ __forceinline__ float ipow(float b, int n) {
    float r = 1.f, p = b;
    while (n) { if (n & 1) r *= p; p *= p; n >>= 1; }
    return r;
}

// M, Dk, Wt
__global__ __launch_bounds__(256) void k0a(const float* __restrict__ W_lin,
                                           const float* __restrict__ W_in,
                                           const float* __restrict__ d,
                                           const float* __restrict__ W_out,
                                           float* __restrict__ ws) {
    int f = blockIdx.x * 256 + threadIdx.x;
    if (f < 800) {                        // Dk[k][r] = d_r^(100k)
        int k = f / RES, r = f % RES;
        ws[OFF_DK + f] = ipow(ipow(d[r], 100), k);
    } else if (f < 5600) {                // Wt[r][o] = W_out[o][r]
        int e = f - 800;
        int r = e / PRED, o = e % PRED;
        ws[OFF_WT + e] = W_out[o * RES + r];
    } else if (f < 8000) {                // M[r][w]
        int e = f - 5600;
        int r = e / WINDOW, w = e % WINDOW;
        float acc = 0.f;
        for (int v = 0; v < WINDOW; ++v)
            acc = fmaf(W_in[r * WINDOW + v], W_lin[v * WINDOW + w], acc);
        ws[OFF_M + e] = acc;
    }
}

// Kb[c][k] = bf16( d_c^(99-j) * M[c][w] ), k = 48j + w ; zero for c>=50 or k>=4800
__global__ __launch_bounds__(256) void k0b(const float* __restrict__ d,
                                           float* __restrict__ ws) {
    unsigned e = blockIdx.x * 256 + threadIdx.x;    // < 64*5120 = 327680
    int c = e / KPAD, k = e - (e / KPAD) * KPAD;
    float val = 0.f;
    if (c < RES && k < KTOT) {
        int j = k / WINDOW, w = k - WINDOW * j;
        val = ipow(d[c], 99 - j) * ws[OFF_M + c * WINDOW + w];
    }
    __hip_bfloat16 h = __float2bfloat16(val);
    ((unsigned short*)(ws + OFF_KB))[e] = __builtin_bit_cast(unsigned short, h);
}

__device__ __forceinline__ void split8(f32x4 a, f32x4 b, short8v& hi, short8v& lo) {
#pragma unroll
    for (int m = 0; m < 8; ++m) {
        float v = (m < 4) ? a[m] : b[m - 4];
        __hip_bfloat16 h = __float2bfloat16(v);           // RNE
        float hf = __bfloat162float(h);
        __hip_bfloat16 l2 = __float2bfloat16(v - hf);
        hi[m] = (short)__builtin_bit_cast(unsigned short, h);
        lo[m] = (short)__builtin_bit_cast(unsigned short, l2);
    }
}

// Block = 4 waves, 16 batch rows x 640 k. Wave w: k slice [w*160, w*160+160).
// A from LDS (exact hi/lo split), B per-lane 16B from L2-resident Kb, 8 MFMA/step.
// Cross-wave reduce via re-aliased LDS -> Lp[s][b][c].
__global__ __launch_bounds__(256, 2) void k1_mfma(const float* __restrict__ x,
                                                  const float* __restrict__ ws,
                                                  float* __restrict__ lp) {
    __shared__ float S[16 * XSTR];        // 41.2 KB; aliased as Ps[4][16][68] later
    const unsigned short* Kb = (const unsigned short*)(ws + OFF_KB);
    int bid = blockIdx.x;
    int s = bid & (KS - 1), mt = bid >> 3;
    int b0 = mt * 16;
    int kb = s * KRB;
    int t = threadIdx.x;
    int w = t >> 6, l = t & 63;
    int row16 = l & 15, kq = l >> 4;

    // --- stage x panel: 16 rows x 160 float4, coalesced, zero-pad k>=4800 ---
#pragma unroll
    for (int i = 0; i < 10; ++i) {
        int e = t + i * 256;              // < 2560
        int row = e / 160, q = e - row * 160;
        float4 v = make_float4(0.f, 0.f, 0.f, 0.f);
        if (kb + 4 * q < KTOT)
            v = *(const float4*)(x + (size_t)(b0 + row) * KTOT + kb + 4 * q);
        *(float4*)(S + row * XSTR + 4 * q) = v;
    }
    __syncthreads();

    f32x4 acc[4];
#pragma unroll
    for (int n = 0; n < 4; ++n) acc[n] = (f32x4)(0.f);

    const unsigned short* kpb = Kb + (size_t)row16 * KPAD + kb;
    int kwb = w * 160 + kq * 8;
#pragma unroll
    for (int st = 0; st < 5; ++st) {
        int koff = kwb + st * 32;
        const float* ap = S + row16 * XSTR + koff;
        f32x4 a0 = *(const f32x4*)ap;
        f32x4 a1 = *(const f32x4*)(ap + 4);
        short8v ahi, alo;
        split8(a0, a1, ahi, alo);
#pragma unroll
        for (int n = 0; n < 4; ++n) {
            short8v bv = *(const short8v*)(kpb + (size_t)(n * 16) * KPAD + koff);
            acc[n] = __builtin_amdgcn_mfma_f32_16x16x32_bf16(ahi, bv, acc[n], 0, 0, 0);
            acc[n] = __builtin_amdgcn_mfma_f32_16x16x32_bf16(alo, bv, acc[n], 0, 0, 0);
        }
    }
    __syncthreads();                       // Xs reads done -> alias as Ps[4][16][68]

    float* Ps = S;
#pragma unroll
    for (int n = 0; n < 4; ++n)
#pragma unroll
        for (int i = 0; i < 4; ++i)
            Ps[w * 1088 + (kq * 4 + i) * 68 + n * 16 + row16] = acc[n][i];
    __syncthreads();

#pragma unroll
    for (int i = 0; i < 4; ++i) {
        int o = t + i * 256;               // < 1024
        int r = o >> 6, c = o & 63;
        float sum = (Ps[r * 68 + c] + Ps[1088 + r * 68 + c])
                  + (Ps[2176 + r * 68 + c] + Ps[3264 + r * 68 + c]);
        lp[((size_t)s * BATCH + b0 + r) * 64 + c] = sum;
    }
}

// L[b][c] = sum_s Lp[s][b][c]
__global__ __launch_bounds__(256) void k2a(float* __restrict__ ws) {
    int e = blockIdx.x * 256 + threadIdx.x;     // < 32768
    const f32x4* lp4 = (const f32x4*)(ws + OFF_LP);
    f32x4 sum = lp4[e];
#pragma unroll
    for (int sp = 1; sp < KS; ++sp)
        sum += lp4[(size_t)sp * 32768 + e];
    ((f32x4*)(ws + OFF_L))[e] = sum;
}

// s[r] = sum_k Dk[k][r]*L[b-k][r]; out[b][o] = sum_r s[r]*Wt[r][o]
__global__ __launch_bounds__(128) void k2b(const float* __restrict__ ws,
                                           float* __restrict__ out) {
    const float* L  = ws + OFF_L;
    const float* Dk = ws + OFF_DK;
    const float* Wt = ws + OFF_WT;
    __shared__ float s_s[52];
    int b = blockIdx.x;
    int t = threadIdx.x;
    if (t < RES) {
        float acc = 0.f;
#pragma unroll
        for (int k = 0; k < KTRUNC; ++k) {
            int bb = b - k;
            if (bb >= 0) acc = fmaf(Dk[k * RES + t], L[(size_t)bb * 64 + t], acc);
        }
        s_s[t] = acc;
    }
    __syncthreads();
    if (t < PRED) {
        float acc = 0.f;
#pragma unroll 10
        for (int r = 0; r < RES; ++r)
            acc = fmaf(s_s[r], Wt[r * PRED + t], acc);
        out[b * PRED + t] = acc;
    }
}

extern "C" void kernel_launch(void* const* d_in, const int* in_sizes, int n_in,
                              void* d_out, int out_size, void* d_ws, size_t ws_size,
                              hipStream_t stream) {
    const float* x     = (const float*)d_in[0];
    const float* W_lin = (const float*)d_in[1];
    const float* W_in  = (const float*)d_in[2];
    const float* d     = (const float*)d_in[3];
    const float* W_out = (const float*)d_in[4];
    float* out = (float*)d_out;
    float* ws  = (float*)d_ws;
    float* lp  = ws + OFF_LP;

    k0a<<<32, 256, 0, stream>>>(W_lin, W_in, d, W_out, ws);
    k0b<<<1280, 256, 0, stream>>>(d, ws);
    k1_mfma<<<128 * KS, 256, 0, stream>>>(x, ws, lp);
    k2a<<<128, 256, 0, stream>>>(ws);
    k2b<<<BATCH, 128, 0, stream>>>(ws, out);
}

// Round 11
// 41.441 us; speedup vs baseline: 1.5194x; 1.0261x over previous
//
#include <hip/hip_runtime.h>
#include <hip/hip_bf16.h>

#define WINDOW 48
#define RES 50
#define PRED 96
#define BATCH 2048
#define KTOT 4800
#define KPAD 5120
#define KTRUNC 12
#define KS 10         // k-splits
#define KRB 512       // k per block (4 waves x 4 steps x 32)
#define XSTR 516      // LDS row stride (floats), 16B-aligned

typedef __attribute__((ext_vector_type(8))) short short8v;   // 8 bf16
typedef __attribute__((ext_vector_type(4))) float f32x4;

// ws float offsets
#define OFF_DK 0          // Dk[16][50]           800
#define OFF_WT 800        // Wt[50][96]           4800  -> 5600
#define OFF_M  5600       // M[50][48]            2400  -> 8000
#define OFF_KB 8000       // ushort Kb[64][5120]  163840 floats -> 171840
#define OFF_LP 171840     // Lp[10][2048][64]     1310720 -> 1482560
#define OFF_L  1482560    // L[2048][64]          131072 -> 1613632 floats (6.5 MB)

__device__ __forceinline__ float ipow(float b, int n) {
    float r = 1.f, p = b;
    while (n) { if (n & 1) r *= p; p *= p; n >>= 1; }
    return r;
}

// RNE f32 -> bf16 (bit ops only), and the residual v - bf16(v)
__device__ __forceinline__ void bsplit(float v, short& h, short& l) {
    unsigned u = __builtin_bit_cast(unsigned, v);
    unsigned hb = (u + 0x7FFFu + ((u >> 16) & 1u)) & 0xFFFF0000u;
    h = (short)(hb >> 16);
    float r = v - __builtin_bit_cast(float, hb);
    unsigned u2 = __builtin_bit_cast(unsigned, r);
    l = (short)((u2 + 0x7FFFu + ((u2 >> 16) & 1u)) >> 16);
}

__global__ __launch_bounds__(256) void k0a(const float* __restrict__ W_lin,
                                           const float* __restrict__ W_in,
                                           const float* __restrict__ d,
                                           const float* __restrict__ W_out,
                                           float* __restrict__ ws) {
    int f = blockIdx.x * 256 + threadIdx.x;
    if (f < 800) {                        // Dk[k][r] = d_r^(100k)
        int k = f / RES, r = f % RES;
        ws[OFF_DK + f] = ipow(ipow(d[r], 100), k);
    } else if (f < 5600) {                // Wt[r][o] = W_out[o][r]
        int e = f - 800;
        int r = e / PRED, o = e % PRED;
        ws[OFF_WT + e] = W_out[o * RES + r];
    } else if (f < 8000) {                // M[r][w]
        int e = f - 5600;
        int r = e / WINDOW, w = e % WINDOW;
        float acc = 0.f;
        for (int v = 0; v < WINDOW; ++v)
            acc = fmaf(W_in[r * WINDOW + v], W_lin[v * WINDOW + w], acc);
        ws[OFF_M + e] = acc;
    }
}

// Kb[c][k] = bf16(d_c^(99-j) * M[c][w]), k = 48j+w; zero for c>=50 or k>=4800
__global__ __launch_bounds__(256) void k0b(const float* __restrict__ d,
                                           float* __restrict__ ws) {
    unsigned e = blockIdx.x * 256 + threadIdx.x;    // < 327680
    int c = e / KPAD, k = e - (e / KPAD) * KPAD;
    float val = 0.f;
    if (c < RES && k < KTOT) {
        int j = k / WINDOW, w = k - WINDOW * j;
        val = ipow(d[c], 99 - j) * ws[OFF_M + c * WINDOW + w];
    }
    unsigned u = __builtin_bit_cast(unsigned, val);
    unsigned hb = (u + 0x7FFFu + ((u >> 16) & 1u)) >> 16;
    ((unsigned short*)(ws + OFF_KB))[e] = (unsigned short)hb;
}

// Block = 4 waves, 16 batch rows x 512 k. Wave w: k slice [w*128, w*128+128).
// All state in named scalars; manual bf16 split; no arrays -> no scratch.
__global__ __launch_bounds__(256, 4) void k1_mfma(const float* __restrict__ x,
                                                  const float* __restrict__ ws,
                                                  float* __restrict__ lp) {
    __shared__ float S[16 * XSTR];        // 33 KB; aliased as Ps[4][16][68] later
    const unsigned short* Kb = (const unsigned short*)(ws + OFF_KB);
    int bid = blockIdx.x;
    int mt = bid / KS, s = bid - mt * KS;
    int b0 = mt * 16;
    int kb = s * KRB;
    int t = threadIdx.x;
    int w = t >> 6, l = t & 63;
    int row16 = l & 15, kq = l >> 4;

    // --- stage x panel: 16 rows x 128 float4, coalesced, zero-pad k>=4800 ---
#pragma unroll
    for (int i = 0; i < 8; ++i) {
        int e = t + i * 256;              // < 2048
        int row = e >> 7, q = e & 127;
        float4 v = make_float4(0.f, 0.f, 0.f, 0.f);
        if (kb + 4 * q < KTOT)
            v = *(const float4*)(x + (size_t)(b0 + row) * KTOT + kb + 4 * q);
        *(float4*)(S + row * XSTR + 4 * q) = v;
    }
    __syncthreads();

    f32x4 acc0 = (f32x4)(0.f), acc1 = (f32x4)(0.f), acc2 = (f32x4)(0.f), acc3 = (f32x4)(0.f);

    const float* ap_base = S + row16 * XSTR + w * 128 + kq * 8;
    const unsigned short* kp = Kb + (size_t)row16 * KPAD + kb + w * 128 + kq * 8;

#pragma unroll
    for (int st = 0; st < 4; ++st) {
        // B loads first (L2-resident Kb) — consumed after the split below
        short8v b0v = *(const short8v*)(kp + (size_t)0 * KPAD + st * 32);
        short8v b1v = *(const short8v*)(kp + (size_t)16 * KPAD + st * 32);
        short8v b2v = *(const short8v*)(kp + (size_t)32 * KPAD + st * 32);
        short8v b3v = *(const short8v*)(kp + (size_t)48 * KPAD + st * 32);

        f32x4 a0 = *(const f32x4*)(ap_base + st * 32);
        f32x4 a1 = *(const f32x4*)(ap_base + st * 32 + 4);

        short8v ahi, alo;
        short h, lo_;
        bsplit(a0[0], h, lo_); ahi[0] = h; alo[0] = lo_;
        bsplit(a0[1], h, lo_); ahi[1] = h; alo[1] = lo_;
        bsplit(a0[2], h, lo_); ahi[2] = h; alo[2] = lo_;
        bsplit(a0[3], h, lo_); ahi[3] = h; alo[3] = lo_;
        bsplit(a1[0], h, lo_); ahi[4] = h; alo[4] = lo_;
        bsplit(a1[1], h, lo_); ahi[5] = h; alo[5] = lo_;
        bsplit(a1[2], h, lo_); ahi[6] = h; alo[6] = lo_;
        bsplit(a1[3], h, lo_); ahi[7] = h; alo[7] = lo_;

        acc0 = __builtin_amdgcn_mfma_f32_16x16x32_bf16(ahi, b0v, acc0, 0, 0, 0);
        acc0 = __builtin_amdgcn_mfma_f32_16x16x32_bf16(alo, b0v, acc0, 0, 0, 0);
        acc1 = __builtin_amdgcn_mfma_f32_16x16x32_bf16(ahi, b1v, acc1, 0, 0, 0);
        acc1 = __builtin_amdgcn_mfma_f32_16x16x32_bf16(alo, b1v, acc1, 0, 0, 0);
        acc2 = __builtin_amdgcn_mfma_f32_16x16x32_bf16(ahi, b2v, acc2, 0, 0, 0);
        acc2 = __builtin_amdgcn_mfma_f32_16x16x32_bf16(alo, b2v, acc2, 0, 0, 0);
        acc3 = __builtin_amdgcn_mfma_f32_16x16x32_bf16(ahi, b3v, acc3, 0, 0, 0);
        acc3 = __builtin_amdgcn_mfma_f32_16x16x32_bf16(alo, b3v, acc3, 0, 0, 0);
    }
    __syncthreads();                       // A-reads done -> alias S as Ps[4][16][68]

    float* Ps = S + w * 1088;
    int pbase = row16;                     // col = channel
#pragma unroll
    for (int i = 0; i < 4; ++i) {
        int rr = (kq * 4 + i) * 68;
        Ps[rr + pbase]      = acc0[i];
        Ps[rr + pbase + 16] = acc1[i];
        Ps[rr + pbase + 32] = acc2[i];
        Ps[rr + pbase + 48] = acc3[i];
    }
    __syncthreads();

#pragma unroll
    for (int i = 0; i < 4; ++i) {
        int o = t + i * 256;               // < 1024
        int r = o >> 6, c = o & 63;
        float sum = (S[r * 68 + c] + S[1088 + r * 68 + c])
                  + (S[2176 + r * 68 + c] + S[3264 + r * 68 + c]);
        lp[((size_t)s * BATCH + b0 + r) * 64 + c] = sum;
    }
}

// L[b][c] = sum_s Lp[s][b][c]
__global__ __launch_bounds__(256) void k2a(float* __restrict__ ws) {
    int e = blockIdx.x * 256 + threadIdx.x;     // < 32768
    const f32x4* lp4 = (const f32x4*)(ws + OFF_LP);
    f32x4 sum = lp4[e];
#pragma unroll
    for (int sp = 1; sp < KS; ++sp)
        sum += lp4[(size_t)sp * 32768 + e];
    ((f32x4*)(ws + OFF_L))[e] = sum;
}

// s[r] = sum_k Dk[k][r]*L[b-k][r]; out[b][o] = sum_r s[r]*Wt[r][o]
__global__ __launch_bounds__(128) void k2b(const float* __restrict__ ws,
                                           float* __restrict__ out) {
    const float* L  = ws + OFF_L;
    const float* Dk = ws + OFF_DK;
    const float* Wt = ws + OFF_WT;
    __shared__ float s_s[52];
    int b = blockIdx.x;
    int t = threadIdx.x;
    if (t < RES) {
        float acc = 0.f;
#pragma unroll
        for (int k = 0; k < KTRUNC; ++k) {
            int bb = b - k;
            if (bb >= 0) acc = fmaf(Dk[k * RES + t], L[(size_t)bb * 64 + t], acc);
        }
        s_s[t] = acc;
    }
    __syncthreads();
    if (t < PRED) {
        float acc = 0.f;
#pragma unroll 10
        for (int r = 0; r < RES; ++r)
            acc = fmaf(s_s[r], Wt[r * PRED + t], acc);
        out[b * PRED + t] = acc;
    }
}

extern "C" void kernel_launch(void* const* d_in, const int* in_sizes, int n_in,
                              void* d_out, int out_size, void* d_ws, size_t ws_size,
                              hipStream_t stream) {
    const float* x     = (const float*)d_in[0];
    const float* W_lin = (const float*)d_in[1];
    const float* W_in  = (const float*)d_in[2];
    const float* d     = (const float*)d_in[3];
    const float* W_out = (const float*)d_in[4];
    float* out = (float*)d_out;
    float* ws  = (float*)d_ws;
    float* lp  = ws + OFF_LP;

    k0a<<<32, 256, 0, stream>>>(W_lin, W_in, d, W_out, ws);
    k0b<<<1280, 256, 0, stream>>>(d, ws);
    k1_mfma<<<128 * KS, 256, 0, stream>>>(x, ws, lp);
    k2a<<<128, 256, 0, stream>>>(ws);
    k2b<<<BATCH, 128, 0, stream>>>(ws, out);
}

// Round 12
// 34.930 us; speedup vs baseline: 1.8026x; 1.1864x over previous
//
#include <hip/hip_runtime.h>

#define WINDOW 48
#define RES 50
#define PRED 96
#define BATCH 2048
#define KTOT 4800
#define KPAD 5120
#define KTRUNC 12
#define KS 10
#define KRB 480       // k per block; waves get 128,128,128,96

typedef __attribute__((ext_vector_type(8))) short short8v;   // 8 bf16
typedef __attribute__((ext_vector_type(4))) float f32x4;

// ws float offsets
#define OFF_DK 0          // Dk[16][50]            800
#define OFF_WT 800        // Wt[50][96]            4800  -> 5600
#define OFF_KB 5600       // ushort Kb[64][5120]   163840 floats -> 169440 (16B-aligned)
#define OFF_LP 169440     // Lp[10][2048][64]      1310720 -> 1480160
#define OFF_L  1480160    // L[2048][64]           131072 -> 1611232 floats (6.4 MB)

__device__ __forceinline__ float ipow(float b, int n) {
    float r = 1.f, p = b;
    while (n) { if (n & 1) r *= p; p *= p; n >>= 1; }
    return r;
}

// One setup kernel: Dk, Wt, and Kb[c][k] = bf16(d_c^(99-j) * M[c][w]) with M inline.
__global__ __launch_bounds__(256) void k0(const float* __restrict__ W_lin,
                                          const float* __restrict__ W_in,
                                          const float* __restrict__ d,
                                          const float* __restrict__ W_out,
                                          float* __restrict__ ws) {
    unsigned f = blockIdx.x * 256 + threadIdx.x;
    if (f < 800) {                        // Dk[k][r] = d_r^(100k)
        int k = f / RES, r = f % RES;
        ws[OFF_DK + f] = ipow(ipow(d[r], 100), k);
    } else if (f < 5600) {                // Wt[r][o] = W_out[o][r]
        int e = f - 800;
        int r = e / PRED, o = e % PRED;
        ws[OFF_WT + e] = W_out[o * RES + r];
    }
    if (f < 64u * KPAD) {                 // Kb
        int c = f / KPAD, k = f - (f / KPAD) * KPAD;
        float val = 0.f;
        if (c < RES && k < KTOT) {
            int j = k / WINDOW, w = k - j * WINDOW;
            float m = 0.f;
            for (int v = 0; v < WINDOW; ++v)
                m = fmaf(W_in[c * WINDOW + v], W_lin[v * WINDOW + w], m);
            val = ipow(d[c], 99 - j) * m;
        }
        unsigned u = __builtin_bit_cast(unsigned, val);
        ((unsigned short*)(ws + OFF_KB))[f] =
            (unsigned short)((u + 0x7FFFu + ((u >> 16) & 1u)) >> 16);
    }
}

// Block = 4 waves over one 16-row x 480-k tile. NO LDS / NO barrier in main loop:
// A read per-lane straight from global x (block consumes full contiguous panel),
// B per-lane 16B from L2-resident Kb. All loads hoisted; exact hi/lo bf16 split.
__global__ __launch_bounds__(256, 3) void k1_mfma(const float* __restrict__ x,
                                                  const float* __restrict__ ws,
                                                  float* __restrict__ lp) {
    __shared__ float Ps[4 * 16 * 68];     // 17.4 KB, epilogue only
    const unsigned short* Kb = (const unsigned short*)(ws + OFF_KB);
    int bid = blockIdx.x;
    int mt = bid / KS, s = bid - mt * KS;
    int b0 = mt * 16, kb = s * KRB;
    int t = threadIdx.x, w = t >> 6, l = t & 63;
    int row16 = l & 15, kq = l >> 4;
    int nst = (w == 3) ? 3 : 4;
    int kw = kb + w * 128 + kq * 8;       // within [kb, kb+480), +8 <= 4800 always

    const float* ap = x + (size_t)(b0 + row16) * KTOT + kw;
    const unsigned short* kp = Kb + (size_t)row16 * KPAD + kw;

    f32x4 A0[4], A1[4];
    short8v B0[4], B1[4], B2[4], B3[4];
#pragma unroll
    for (int st = 0; st < 4; ++st) if (st < nst) {
        A0[st] = *(const f32x4*)(ap + st * 32);
        A1[st] = *(const f32x4*)(ap + st * 32 + 4);
        B0[st] = *(const short8v*)(kp + (size_t)0  * KPAD + st * 32);
        B1[st] = *(const short8v*)(kp + (size_t)16 * KPAD + st * 32);
        B2[st] = *(const short8v*)(kp + (size_t)32 * KPAD + st * 32);
        B3[st] = *(const short8v*)(kp + (size_t)48 * KPAD + st * 32);
    }

    f32x4 acc0 = (f32x4)(0.f), acc1 = (f32x4)(0.f), acc2 = (f32x4)(0.f), acc3 = (f32x4)(0.f);
#pragma unroll
    for (int st = 0; st < 4; ++st) if (st < nst) {
        short8v ahi, alo;
#pragma unroll
        for (int m = 0; m < 8; ++m) {
            float v = (m < 4) ? A0[st][m] : A1[st][m - 4];
            unsigned u = __builtin_bit_cast(unsigned, v);
            unsigned hb = (u + 0x7FFFu + ((u >> 16) & 1u)) & 0xFFFF0000u;
            ahi[m] = (short)(hb >> 16);
            float r = v - __builtin_bit_cast(float, hb);
            unsigned u2 = __builtin_bit_cast(unsigned, r);
            alo[m] = (short)((u2 + 0x7FFFu + ((u2 >> 16) & 1u)) >> 16);
        }
        acc0 = __builtin_amdgcn_mfma_f32_16x16x32_bf16(ahi, B0[st], acc0, 0, 0, 0);
        acc0 = __builtin_amdgcn_mfma_f32_16x16x32_bf16(alo, B0[st], acc0, 0, 0, 0);
        acc1 = __builtin_amdgcn_mfma_f32_16x16x32_bf16(ahi, B1[st], acc1, 0, 0, 0);
        acc1 = __builtin_amdgcn_mfma_f32_16x16x32_bf16(alo, B1[st], acc1, 0, 0, 0);
        acc2 = __builtin_amdgcn_mfma_f32_16x16x32_bf16(ahi, B2[st], acc2, 0, 0, 0);
        acc2 = __builtin_amdgcn_mfma_f32_16x16x32_bf16(alo, B2[st], acc2, 0, 0, 0);
        acc3 = __builtin_amdgcn_mfma_f32_16x16x32_bf16(ahi, B3[st], acc3, 0, 0, 0);
        acc3 = __builtin_amdgcn_mfma_f32_16x16x32_bf16(alo, B3[st], acc3, 0, 0, 0);
    }

    // cross-wave reduce via LDS (only sync points in the kernel)
    float* P = Ps + w * 1088;
#pragma unroll
    for (int i = 0; i < 4; ++i) {
        int rr = (kq * 4 + i) * 68;
        P[rr + row16]      = acc0[i];
        P[rr + row16 + 16] = acc1[i];
        P[rr + row16 + 32] = acc2[i];
        P[rr + row16 + 48] = acc3[i];
    }
    __syncthreads();
#pragma unroll
    for (int i = 0; i < 4; ++i) {
        int o = t + i * 256;               // < 1024
        int r = o >> 6, c = o & 63;
        float sum = (Ps[r * 68 + c] + Ps[1088 + r * 68 + c])
                  + (Ps[2176 + r * 68 + c] + Ps[3264 + r * 68 + c]);
        lp[((size_t)s * BATCH + b0 + r) * 64 + c] = sum;
    }
}

// L[b][c] = sum_s Lp[s][b][c]
__global__ __launch_bounds__(256) void k2a(float* __restrict__ ws) {
    int e = blockIdx.x * 256 + threadIdx.x;     // < 32768
    const f32x4* lp4 = (const f32x4*)(ws + OFF_LP);
    f32x4 sum = lp4[e];
#pragma unroll
    for (int sp = 1; sp < KS; ++sp)
        sum += lp4[(size_t)sp * 32768 + e];
    ((f32x4*)(ws + OFF_L))[e] = sum;
}

// s[r] = sum_k Dk[k][r]*L[b-k][r]; out[b][o] = sum_r s[r]*Wt[r][o]
__global__ __launch_bounds__(128) void k2b(const float* __restrict__ ws,
                                           float* __restrict__ out) {
    const float* L  = ws + OFF_L;
    const float* Dk = ws + OFF_DK;
    const float* Wt = ws + OFF_WT;
    __shared__ float s_s[52];
    int b = blockIdx.x;
    int t = threadIdx.x;
    if (t < RES) {
        float acc = 0.f;
#pragma unroll
        for (int k = 0; k < KTRUNC; ++k) {
            int bb = b - k;
            if (bb >= 0) acc = fmaf(Dk[k * RES + t], L[(size_t)bb * 64 + t], acc);
        }
        s_s[t] = acc;
    }
    __syncthreads();
    if (t < PRED) {
        float acc = 0.f;
#pragma unroll 10
        for (int r = 0; r < RES; ++r)
            acc = fmaf(s_s[r], Wt[r * PRED + t], acc);
        out[b * PRED + t] = acc;
    }
}

extern "C" void kernel_launch(void* const* d_in, const int* in_sizes, int n_in,
                              void* d_out, int out_size, void* d_ws, size_t ws_size,
                              hipStream_t stream) {
    const float* x     = (const float*)d_in[0];
    const float* W_lin = (const float*)d_in[1];
    const float* W_in  = (const float*)d_in[2];
    const float* d     = (const float*)d_in[3];
    const float* W_out = (const float*)d_in[4];
    float* out = (float*)d_out;
    float* ws  = (float*)d_ws;
    float* lp  = ws + OFF_LP;

    k0<<<1280, 256, 0, stream>>>(W_lin, W_in, d, W_out, ws);
    k1_mfma<<<128 * KS, 256, 0, stream>>>(x, ws, lp);
    k2a<<<128, 256, 0, stream>>>(ws);
    k2b<<<BATCH, 128, 0, stream>>>(ws, out);
}